// Round 1
// baseline (372.060 us; speedup 1.0000x reference)
//
#include <hip/hip_runtime.h>
#include <hip/hip_bf16.h>
#include <stdint.h>

typedef __bf16 bf16x8 __attribute__((ext_vector_type(8)));
typedef float f32x4 __attribute__((ext_vector_type(4)));

#define GLD16(gp, lp) __builtin_amdgcn_global_load_lds( \
    (__attribute__((address_space(1))) void*)(gp),      \
    (__attribute__((address_space(3))) void*)(lp), 16, 0, 0)

// Sizes
#define Bb 4
#define Nn 8192
#define Mm 2048
#define Cc 512
#define Ll 256
#define Hh 8
#define dLL 32
#define dCC 64

// ---------------- K0a: convert X (16.8M) and Q (4.2M) f32 -> bf16 ----------
__global__ __launch_bounds__(256) void convert_bf16(
    const float* __restrict__ X, const float* __restrict__ Q,
    __hip_bfloat16* __restrict__ dst /* Xb followed by Qb contiguous */)
{
    const long NX = (long)Bb * Nn * Cc;           // 16777216
    const long NT = NX + (long)Bb * Mm * Cc;      // 20971520
    long i = ((long)blockIdx.x * 256 + threadIdx.x) * 8;
    if (i >= NT) return;
    const float* src; long off;
    if (i < NX) { src = X; off = i; } else { src = Q; off = i - NX; }
    float4 a = *(const float4*)(src + off);
    float4 b = *(const float4*)(src + off + 4);
    __hip_bfloat16 t8[8] = {
        __float2bfloat16(a.x), __float2bfloat16(a.y),
        __float2bfloat16(a.z), __float2bfloat16(a.w),
        __float2bfloat16(b.x), __float2bfloat16(b.y),
        __float2bfloat16(b.z), __float2bfloat16(b.w)};
    *(uint4*)(dst + i) = *(const uint4*)t8;
}

// ---------------- K0b: build transposed bf16 weights ------------------------
// Wkvt[j][c], j<256 -> Wk[c][j]; j>=256 -> Wv[c][j-256].  Wqt[j][c] = Wq[c][j]
__global__ __launch_bounds__(256) void transpose_w(
    const float* __restrict__ Wk, const float* __restrict__ Wv,
    const float* __restrict__ Wq,
    __hip_bfloat16* __restrict__ Wkvt, __hip_bfloat16* __restrict__ Wqt)
{
    int idx = blockIdx.x * 256 + threadIdx.x;
    const int NKV = 768 * 512;
    if (idx < NKV) {
        int j = idx >> 9, c = idx & 511;
        float v = (j < 256) ? Wk[c * 256 + j] : Wv[c * 512 + (j - 256)];
        Wkvt[idx] = __float2bfloat16(v);
    } else {
        int k = idx - NKV;
        int j = k >> 9, c = k & 511;
        Wqt[k] = __float2bfloat16(Wq[c * 256 + j]);
    }
}

// ---------------- GEMM: C = A(MxK) @ Bt(NxK)^T, bf16, fused epilogue --------
// BM=BN=128, BK=32, 256 threads (4 waves, 2x2), m97-style gload_lds staging.
// MODE 0: kv epilogue (col<256: +bk, elu+1 ; col>=256: +bv), out stride 768
// MODE 1: q  epilogue (+bq, elu+1), out stride Ndim
template<int MODE>
__global__ __launch_bounds__(256)
void gemm_bt(const __hip_bfloat16* __restrict__ A,
             const __hip_bfloat16* __restrict__ Bt,
             const float* __restrict__ bias0, const float* __restrict__ bias1,
             __hip_bfloat16* __restrict__ C,
             int Mdim, int Ndim, int Kdim)
{
    __shared__ __hip_bfloat16 lA[128 * 32];
    __shared__ __hip_bfloat16 lB[128 * 32];
    const int tid  = threadIdx.x;
    const int lane = tid & 63;
    const int wv   = tid >> 6;
    const int wm   = wv >> 1, wn = wv & 1;
    const long gm0 = (long)blockIdx.x * 128;
    const long gn0 = (long)blockIdx.y * 128;

    // staging: 2 rounds of 16B per thread per operand
    const int o0 = tid * 16;            // LDS byte offset round 0
    const int row0 = o0 >> 6;           // 0..63
    const int kb0 = o0 & 63;            // byte within 64B row
    const int o1 = o0 + 4096;
    const int row1 = row0 + 64;
    const char* Apc = (const char*)A;
    const char* Bpc = (const char*)Bt;
    const long stride = (long)Kdim * 2; // row bytes
    char* lApc = (char*)lA;
    char* lBpc = (char*)lB;

    f32x4 acc[4][4];
#pragma unroll
    for (int i = 0; i < 4; i++)
#pragma unroll
        for (int j = 0; j < 4; j++) acc[i][j] = (f32x4){0.f, 0.f, 0.f, 0.f};

    const int l16 = lane & 15, lq = lane >> 4;
    int aoff[4], boff[4];
#pragma unroll
    for (int i = 0; i < 4; i++) {
        aoff[i] = (wm * 64 + i * 16 + l16) * 64 + lq * 16;
        boff[i] = (wn * 64 + i * 16 + l16) * 64 + lq * 16;
    }

    const int KT = Kdim >> 5;
    for (int kt = 0; kt < KT; ++kt) {
        const long kbyte = (long)kt * 64;
        GLD16(Apc + (gm0 + row0) * stride + kbyte + kb0, lApc + o0);
        GLD16(Apc + (gm0 + row1) * stride + kbyte + kb0, lApc + o1);
        GLD16(Bpc + (gn0 + row0) * stride + kbyte + kb0, lBpc + o0);
        GLD16(Bpc + (gn0 + row1) * stride + kbyte + kb0, lBpc + o1);
        __syncthreads();
        bf16x8 af[4], bfr[4];
#pragma unroll
        for (int i = 0; i < 4; i++) af[i]  = *(const bf16x8*)(lApc + aoff[i]);
#pragma unroll
        for (int j = 0; j < 4; j++) bfr[j] = *(const bf16x8*)(lBpc + boff[j]);
#pragma unroll
        for (int i = 0; i < 4; i++)
#pragma unroll
            for (int j = 0; j < 4; j++)
                acc[i][j] = __builtin_amdgcn_mfma_f32_16x16x32_bf16(
                    af[i], bfr[j], acc[i][j], 0, 0, 0);
        __syncthreads();
    }

    // epilogue: C/D layout col=lane&15, row=(lane>>4)*4+reg  [m89-verified]
    const long ostride = (MODE == 0) ? 768 : Ndim;
#pragma unroll
    for (int i = 0; i < 4; i++) {
        const long gmr = gm0 + wm * 64 + i * 16 + lq * 4;
#pragma unroll
        for (int j = 0; j < 4; j++) {
            const int gn = (int)gn0 + wn * 64 + j * 16 + l16;
            float bias;
            bool act;
            if (MODE == 0) {
                act = (gn < 256);
                bias = act ? bias0[gn] : bias1[gn - 256];
            } else {
                act = true;
                bias = bias0[gn];
            }
#pragma unroll
            for (int v = 0; v < 4; v++) {
                float x = acc[i][j][v] + bias;
                if (act) x = (x > 0.f) ? x + 1.f : __expf(x);
                C[(gmr + v) * ostride + gn] = __float2bfloat16(x);
            }
        }
    }
}

// ---------------- K2: kv aggregation + ksum ---------------------------------
// kvagg[b][h][c][d] = sum_n v[n,c]*k[n,d];  ksum[b][h][d] = sum_n k[n,d]
// grid (32 chunks of 256 tokens, 8 heads, 4 batch); 256 thr: c=t&63, dg=t>>6
__global__ __launch_bounds__(256)
void kv_reduce(const __hip_bfloat16* __restrict__ kvb,
               float* __restrict__ kvagg, float* __restrict__ ksum)
{
    const int b = blockIdx.z, h = blockIdx.y, ch = blockIdx.x;
    const int t = threadIdx.x;
    const int c = t & 63, dg = t >> 6;
    const long base = ((long)b * Nn + ch * 256) * 768;
    const __hip_bfloat16* pk = kvb + base + h * 32 + dg * 8;
    const __hip_bfloat16* pv = kvb + base + 256 + h * 64 + c;
    float acc[8] = {0, 0, 0, 0, 0, 0, 0, 0};
    float kacc[8] = {0, 0, 0, 0, 0, 0, 0, 0};
    for (int n = 0; n < 256; ++n) {
        bf16x8 k8 = *(const bf16x8*)(pk + (long)n * 768);
        float vv = __bfloat162float(pv[(long)n * 768]);
        float kf[8];
#pragma unroll
        for (int d = 0; d < 8; ++d) kf[d] = (float)k8[d];
#pragma unroll
        for (int d = 0; d < 8; ++d) acc[d] = fmaf(vv, kf[d], acc[d]);
        if (c == 0) {
#pragma unroll
            for (int d = 0; d < 8; ++d) kacc[d] += kf[d];
        }
    }
    float* kvout = kvagg + (((long)b * Hh + h) * 64 + c) * 32 + dg * 8;
#pragma unroll
    for (int d = 0; d < 8; ++d) atomicAdd(kvout + d, acc[d]);
    if (c == 0) {
        float* ks = ksum + ((long)b * Hh + h) * 32 + dg * 8;
#pragma unroll
        for (int d = 0; d < 8; ++d) atomicAdd(ks + d, kacc[d]);
    }
}

// ---------------- K2b: z[m][h] = 1/(q[m,h,:].ksum[b,h,:] + eps) -------------
__global__ __launch_bounds__(256)
void z_kernel(const __hip_bfloat16* __restrict__ qb,
              const float* __restrict__ ksum, float* __restrict__ zb)
{
    int t = blockIdx.x * 256 + threadIdx.x;  // 65536 = 8192*8
    int m = t >> 3, h = t & 7;
    int b = m >> 11;
    const __hip_bfloat16* q = qb + (long)m * 256 + h * 32;
    const float* ks = ksum + ((long)b * Hh + h) * 32;
    float s = 0.f;
#pragma unroll
    for (int d8 = 0; d8 < 4; ++d8) {
        bf16x8 qv = *(const bf16x8*)(q + d8 * 8);
#pragma unroll
        for (int u = 0; u < 8; ++u) s = fmaf((float)qv[u], ks[d8 * 8 + u], s);
    }
    zb[t] = 1.f / (s + 1e-6f);
}

// ---------------- K3: out[m, h*64+c] = z[m,h] * sum_d q[m,h,d]*kv[h,c,d] ----
// TM=32 rows/block; kv in regs (2 (h,c) pairs/thread), q tile f32 in LDS.
__global__ __launch_bounds__(256)
void out_kernel(const __hip_bfloat16* __restrict__ qb,
                const float* __restrict__ kvagg, const float* __restrict__ zb,
                float* __restrict__ out)
{
    __shared__ float lqf[32 * 256];  // 32KB
    __shared__ float lz[32 * 8];
    const int b = blockIdx.y, mt = blockIdx.x;
    const int t = threadIdx.x;
    const long qrow0 = (long)b * Mm + mt * 32;

    // stage q tile (32x256 bf16) -> f32 LDS
#pragma unroll
    for (int r = 0; r < 4; ++r) {
        int e = (r * 256 + t) * 8;  // 0..8191
        bf16x8 qv = *(const bf16x8*)(qb + qrow0 * 256 + e);
        f32x4 lo = {(float)qv[0], (float)qv[1], (float)qv[2], (float)qv[3]};
        f32x4 hi = {(float)qv[4], (float)qv[5], (float)qv[6], (float)qv[7]};
        *(f32x4*)&lqf[e] = lo;
        *(f32x4*)&lqf[e + 4] = hi;
    }
    if (t < 256) {  // all threads: 256 z values
        lz[t] = zb[qrow0 * 8 + t];
    }
    // kv registers: pair0 = t, pair1 = t+256;  p = h*64+c
    float kv0[32], kv1[32];
    const float* kvb = kvagg + (long)b * (Hh * 64 * 32);
#pragma unroll
    for (int d4 = 0; d4 < 8; ++d4) {
        *(f32x4*)&kv0[d4 * 4] = *(const f32x4*)&kvb[(long)t * 32 + d4 * 4];
        *(f32x4*)&kv1[d4 * 4] = *(const f32x4*)&kvb[((long)t + 256) * 32 + d4 * 4];
    }
    __syncthreads();

    const int h0 = t >> 6;  // pair0 head; pair1 head = h0+4
    for (int r = 0; r < 32; ++r) {
        float a0 = 0.f, a1 = 0.f;
        const float* q0 = &lqf[r * 256 + h0 * 32];
        const float* q1 = q0 + 128;
#pragma unroll
        for (int d = 0; d < 32; ++d) {
            a0 = fmaf(q0[d], kv0[d], a0);
            a1 = fmaf(q1[d], kv1[d], a1);
        }
        const float z0 = lz[r * 8 + h0];
        const float z1 = lz[r * 8 + h0 + 4];
        const long ob = (qrow0 + r) * 512;
        out[ob + t] = a0 * z0;
        out[ob + t + 256] = a1 * z1;
    }
}

// ---------------- launch ----------------------------------------------------
extern "C" void kernel_launch(void* const* d_in, const int* in_sizes, int n_in,
                              void* d_out, int out_size, void* d_ws, size_t ws_size,
                              hipStream_t stream)
{
    const float* X  = (const float*)d_in[0];
    const float* Qt = (const float*)d_in[1];
    const float* Wq = (const float*)d_in[2];
    const float* bq = (const float*)d_in[3];
    const float* Wk = (const float*)d_in[4];
    const float* bk = (const float*)d_in[5];
    const float* Wv = (const float*)d_in[6];
    const float* bv = (const float*)d_in[7];
    float* out = (float*)d_out;

    // workspace layout (bytes ~98 MB)
    __hip_bfloat16* Xb    = (__hip_bfloat16*)d_ws;                 // 32768*512
    __hip_bfloat16* Qb    = Xb + (long)32768 * 512;                // 8192*512
    __hip_bfloat16* Wkvt  = Qb + (long)8192 * 512;                 // 768*512
    __hip_bfloat16* Wqt   = Wkvt + 768 * 512;                      // 256*512
    __hip_bfloat16* kvbuf = Wqt + 256 * 512;                       // 32768*768
    __hip_bfloat16* qbuf  = kvbuf + (long)32768 * 768;             // 8192*256
    float* kvagg = (float*)(qbuf + (long)8192 * 256);              // 4*8*64*32
    float* ksum  = kvagg + 4 * 8 * 64 * 32;                        // 4*8*32
    float* zbuf  = ksum + 4 * 8 * 32;                              // 8192*8

    hipMemsetAsync(kvagg, 0, (4 * 8 * 64 * 32 + 4 * 8 * 32) * sizeof(float), stream);

    convert_bf16<<<10240, 256, 0, stream>>>(X, Qt, Xb);
    transpose_w<<<2048, 256, 0, stream>>>(Wk, Wv, Wq, Wkvt, Wqt);
    gemm_bt<0><<<dim3(256, 6), 256, 0, stream>>>(Xb, Wkvt, bk, bv, kvbuf, 32768, 768, 512);
    gemm_bt<1><<<dim3(64, 2), 256, 0, stream>>>(Qb, Wqt, bq, nullptr, qbuf, 8192, 256, 512);
    kv_reduce<<<dim3(32, 8, 4), 256, 0, stream>>>(kvbuf, kvagg, ksum);
    z_kernel<<<256, 256, 0, stream>>>(qbuf, ksum, zbuf);
    out_kernel<<<dim3(64, 4), 256, 0, stream>>>(qbuf, kvagg, zbuf, out);
}

// Round 2
// 219.671 us; speedup vs baseline: 1.6937x; 1.6937x over previous
//
#include <hip/hip_runtime.h>
#include <hip/hip_bf16.h>
#include <stdint.h>

typedef __bf16 bf16x8 __attribute__((ext_vector_type(8)));
typedef float f32x4 __attribute__((ext_vector_type(4)));

#define GLD16(gp, lp) __builtin_amdgcn_global_load_lds( \
    (__attribute__((address_space(1))) void*)(gp),      \
    (__attribute__((address_space(3))) void*)(lp), 16, 0, 0)

// Sizes
#define Bb 4
#define Nn 8192
#define Mm 2048
#define Cc 512
#define Ll 256
#define Hh 8
#define dLL 32
#define dCC 64
#define NTOK 32768   // Bb*Nn

// ---------------- K0a: convert X (16.8M) and Q (4.2M) f32 -> bf16 ----------
__global__ __launch_bounds__(256) void convert_bf16(
    const float* __restrict__ X, const float* __restrict__ Q,
    __hip_bfloat16* __restrict__ dst /* Xb followed by Qb contiguous */)
{
    const long NX = (long)Bb * Nn * Cc;           // 16777216
    const long NT = NX + (long)Bb * Mm * Cc;      // 20971520
    long i = ((long)blockIdx.x * 256 + threadIdx.x) * 8;
    if (i >= NT) return;
    const float* src; long off;
    if (i < NX) { src = X; off = i; } else { src = Q; off = i - NX; }
    float4 a = *(const float4*)(src + off);
    float4 b = *(const float4*)(src + off + 4);
    __hip_bfloat16 t8[8] = {
        __float2bfloat16(a.x), __float2bfloat16(a.y),
        __float2bfloat16(a.z), __float2bfloat16(a.w),
        __float2bfloat16(b.x), __float2bfloat16(b.y),
        __float2bfloat16(b.z), __float2bfloat16(b.w)};
    *(uint4*)(dst + i) = *(const uint4*)t8;
}

// ---------------- K0b: build transposed bf16 weights ------------------------
__global__ __launch_bounds__(256) void transpose_w(
    const float* __restrict__ Wk, const float* __restrict__ Wv,
    const float* __restrict__ Wq,
    __hip_bfloat16* __restrict__ Wkvt, __hip_bfloat16* __restrict__ Wqt)
{
    int idx = blockIdx.x * 256 + threadIdx.x;
    const int NKV = 768 * 512;
    if (idx < NKV) {
        int j = idx >> 9, c = idx & 511;
        float v = (j < 256) ? Wk[c * 256 + j] : Wv[c * 512 + (j - 256)];
        Wkvt[idx] = __float2bfloat16(v);
    } else {
        int k = idx - NKV;
        int j = k >> 9, c = k & 511;
        Wqt[k] = __float2bfloat16(Wq[c * 256 + j]);
    }
}

// ---------------- GEMM: C = A(MxK) @ Bt(NxK)^T, bf16, fused epilogue --------
// MODE 0: kv epilogue (col<256: +bk, elu+1 ; col>=256: +bv),
//         output TRANSPOSED: C[gn][token], token-stride = Mdim
// MODE 1: q epilogue (+bq, elu+1), natural layout, out stride Ndim
template<int MODE>
__global__ __launch_bounds__(256)
void gemm_bt(const __hip_bfloat16* __restrict__ A,
             const __hip_bfloat16* __restrict__ Bt,
             const float* __restrict__ bias0, const float* __restrict__ bias1,
             __hip_bfloat16* __restrict__ C,
             int Mdim, int Ndim, int Kdim)
{
    __shared__ __hip_bfloat16 lA[128 * 32];
    __shared__ __hip_bfloat16 lB[128 * 32];
    const int tid  = threadIdx.x;
    const int lane = tid & 63;
    const int wv   = tid >> 6;
    const int wm   = wv >> 1, wn = wv & 1;
    const long gm0 = (long)blockIdx.x * 128;
    const long gn0 = (long)blockIdx.y * 128;

    const int o0 = tid * 16;
    const int row0 = o0 >> 6;
    const int kb0 = o0 & 63;
    const int o1 = o0 + 4096;
    const int row1 = row0 + 64;
    const char* Apc = (const char*)A;
    const char* Bpc = (const char*)Bt;
    const long stride = (long)Kdim * 2;
    char* lApc = (char*)lA;
    char* lBpc = (char*)lB;

    f32x4 acc[4][4];
#pragma unroll
    for (int i = 0; i < 4; i++)
#pragma unroll
        for (int j = 0; j < 4; j++) acc[i][j] = (f32x4){0.f, 0.f, 0.f, 0.f};

    const int l16 = lane & 15, lq = lane >> 4;
    int aoff[4], boff[4];
#pragma unroll
    for (int i = 0; i < 4; i++) {
        aoff[i] = (wm * 64 + i * 16 + l16) * 64 + lq * 16;
        boff[i] = (wn * 64 + i * 16 + l16) * 64 + lq * 16;
    }

    const int KT = Kdim >> 5;
    for (int kt = 0; kt < KT; ++kt) {
        const long kbyte = (long)kt * 64;
        GLD16(Apc + (gm0 + row0) * stride + kbyte + kb0, lApc + o0);
        GLD16(Apc + (gm0 + row1) * stride + kbyte + kb0, lApc + o1);
        GLD16(Bpc + (gn0 + row0) * stride + kbyte + kb0, lBpc + o0);
        GLD16(Bpc + (gn0 + row1) * stride + kbyte + kb0, lBpc + o1);
        __syncthreads();
        bf16x8 af[4], bfr[4];
#pragma unroll
        for (int i = 0; i < 4; i++) af[i]  = *(const bf16x8*)(lApc + aoff[i]);
#pragma unroll
        for (int j = 0; j < 4; j++) bfr[j] = *(const bf16x8*)(lBpc + boff[j]);
#pragma unroll
        for (int i = 0; i < 4; i++)
#pragma unroll
            for (int j = 0; j < 4; j++)
                acc[i][j] = __builtin_amdgcn_mfma_f32_16x16x32_bf16(
                    af[i], bfr[j], acc[i][j], 0, 0, 0);
        __syncthreads();
    }

    // epilogue: C/D layout col=lane&15, row=(lane>>4)*4+reg  [m89-verified]
#pragma unroll
    for (int i = 0; i < 4; i++) {
        const long gmr = gm0 + wm * 64 + i * 16 + lq * 4;
#pragma unroll
        for (int j = 0; j < 4; j++) {
            const int gn = (int)gn0 + wn * 64 + j * 16 + l16;
            float bias;
            bool act;
            if (MODE == 0) {
                act = (gn < 256);
                bias = act ? bias0[gn] : bias1[gn - 256];
            } else {
                act = true;
                bias = bias0[gn];
            }
            if (MODE == 0) {
                __hip_bfloat16 o4[4];
#pragma unroll
                for (int v = 0; v < 4; v++) {
                    float x = acc[i][j][v] + bias;
                    if (act) x = (x > 0.f) ? x + 1.f : __expf(x);
                    o4[v] = __float2bfloat16(x);
                }
                *(ushort4*)(&C[(long)gn * Mdim + gmr]) = *(const ushort4*)o4;
            } else {
#pragma unroll
                for (int v = 0; v < 4; v++) {
                    float x = acc[i][j][v] + bias;
                    x = (x > 0.f) ? x + 1.f : __expf(x);
                    C[(gmr + v) * (long)Ndim + gn] = __float2bfloat16(x);
                }
            }
        }
    }
}

// ---------------- kv_mfma: kvpart[b,h,chunk,c,d] = sum_n v[n,c]*k[n,d] ------
// Reads kvT [768 feat][32768 tok]. Per block: one (b,h) and a 512-token chunk.
// LDS tiles (64 tok): kT[32][64], vT[64][64], XOR-swizzled via pre-swizzled
// global source (linear global_load_lds dest + swizzled ds_read). 2-phase.
__global__ __launch_bounds__(256)
void kv_mfma(const __hip_bfloat16* __restrict__ kvT, float* __restrict__ kvpart)
{
    __shared__ char lds[2][12288];
    const int chunk = blockIdx.x, h = blockIdx.y, b = blockIdx.z;
    const int t = threadIdx.x;
    const long RS = (long)NTOK * 2;                    // feature-row stride bytes
    const long tokB0 = (long)b * (Nn * 2) + chunk * 1024;  // 512 tok * 2B
    const char* kc = (const char*)kvT;
    const int r = t >> 3;                              // staging row 0..31
    const int wsw = ((t * 16) & 127) ^ ((r & 7) << 4); // pre-swizzled src byte
    const char* pK  = kc + (h * 32 + r) * RS + tokB0 + wsw;
    const char* pV0 = kc + (256 + h * 64 + r) * RS + tokB0 + wsw;
    const char* pV1 = pV0 + 32 * RS;

    const int w = t >> 6, l16 = t & 15, lq = (t >> 4) & 3;
    const int arow = w * 16 + l16;
    int aoffs[2], boffs[2][2];
#pragma unroll
    for (int ks = 0; ks < 2; ++ks) {
        const int wb = ks * 64 + lq * 16;
        aoffs[ks] = arow * 128 + (wb ^ ((arow & 7) << 4));
        boffs[ks][0] = l16 * 128 + (wb ^ ((l16 & 7) << 4));
        boffs[ks][1] = boffs[ks][0] + 2048;            // row+16, same (&7)
    }

    f32x4 acc0 = {0.f, 0.f, 0.f, 0.f}, acc1 = {0.f, 0.f, 0.f, 0.f};

    {   // prologue: stage K-tile 0
        char* bf = lds[0];
        GLD16(pK,  bf + t * 16);
        GLD16(pV0, bf + 4096 + t * 16);
        GLD16(pV1, bf + 8192 + t * 16);
    }
    __syncthreads();
    int cur = 0;
    for (int kt = 0; kt < 8; ++kt) {
        if (kt < 7) {
            char* bf = lds[cur ^ 1];
            const long kb = (long)(kt + 1) * 128;
            GLD16(pK + kb,  bf + t * 16);
            GLD16(pV0 + kb, bf + 4096 + t * 16);
            GLD16(pV1 + kb, bf + 8192 + t * 16);
        }
        const char* lK = lds[cur];
        const char* lV = lds[cur] + 4096;
#pragma unroll
        for (int ks = 0; ks < 2; ++ks) {
            bf16x8 av = *(const bf16x8*)(lV + aoffs[ks]);
            bf16x8 b0 = *(const bf16x8*)(lK + boffs[ks][0]);
            bf16x8 b1 = *(const bf16x8*)(lK + boffs[ks][1]);
            acc0 = __builtin_amdgcn_mfma_f32_16x16x32_bf16(av, b0, acc0, 0, 0, 0);
            acc1 = __builtin_amdgcn_mfma_f32_16x16x32_bf16(av, b1, acc1, 0, 0, 0);
        }
        __syncthreads();
        cur ^= 1;
    }

    // D layout: row c = w*16 + lq*4 + v, col d = (dt*16) + l16
    float* op = kvpart + (((long)(b * 8 + h) * 16 + chunk) * 2048);
#pragma unroll
    for (int v = 0; v < 4; ++v) {
        const int c = w * 16 + lq * 4 + v;
        op[c * 32 + l16]      = acc0[v];
        op[c * 32 + 16 + l16] = acc1[v];
    }
}

// ---------------- reduce kvpart (16 chunks) -> kvagg ------------------------
__global__ __launch_bounds__(256)
void reduce_kv(const float* __restrict__ part, float* __restrict__ kvagg)
{
    int idx = blockIdx.x * 256 + threadIdx.x;   // 0..65535
    int bh = idx >> 11, cd = idx & 2047;
    const float* p = part + (long)bh * 16 * 2048 + cd;
    float s = 0.f;
#pragma unroll
    for (int ch = 0; ch < 16; ++ch) s += p[ch * 2048];
    kvagg[idx] = s;
}

// ---------------- ksum[b][j] = sum_n kT[j][b*8192 + n] ----------------------
__global__ __launch_bounds__(256)
void ksum_kernel(const __hip_bfloat16* __restrict__ kvT, float* __restrict__ ksum)
{
    const int j = blockIdx.x;   // 0..255 (= h*32+d)
    const int b = blockIdx.y;
    const int t = threadIdx.x;
    const __hip_bfloat16* row = kvT + (long)j * NTOK + b * Nn + t * 32;
    float s = 0.f;
#pragma unroll
    for (int u = 0; u < 4; ++u) {
        bf16x8 kv8 = *(const bf16x8*)(row + u * 8);
#pragma unroll
        for (int e = 0; e < 8; ++e) s += (float)kv8[e];
    }
    __shared__ float red[256];
    red[t] = s;
    __syncthreads();
    for (int st = 128; st > 0; st >>= 1) {
        if (t < st) red[t] += red[t + st];
        __syncthreads();
    }
    if (t == 0) ksum[b * 256 + j] = red[0];
}

// ---------------- z[m][h] = 1/(q[m,h,:].ksum[b,h,:] + eps) ------------------
__global__ __launch_bounds__(256)
void z_kernel(const __hip_bfloat16* __restrict__ qb,
              const float* __restrict__ ksum, float* __restrict__ zb)
{
    int t = blockIdx.x * 256 + threadIdx.x;  // 65536 = 8192*8
    int m = t >> 3, h = t & 7;
    int b = m >> 11;
    const __hip_bfloat16* q = qb + (long)m * 256 + h * 32;
    const float* ks = ksum + ((long)b * Hh + h) * 32;
    float s = 0.f;
#pragma unroll
    for (int d8 = 0; d8 < 4; ++d8) {
        bf16x8 qv = *(const bf16x8*)(q + d8 * 8);
#pragma unroll
        for (int u = 0; u < 8; ++u) s = fmaf((float)qv[u], ks[d8 * 8 + u], s);
    }
    zb[t] = 1.f / (s + 1e-6f);
}

// ---------------- out[m, h*64+c] = z[m,h] * sum_d q[m,h,d]*kv[h,c,d] --------
__global__ __launch_bounds__(256)
void out_kernel(const __hip_bfloat16* __restrict__ qb,
                const float* __restrict__ kvagg, const float* __restrict__ zb,
                float* __restrict__ out)
{
    __shared__ float lqf[32 * 256];  // 32KB
    __shared__ float lz[32 * 8];
    const int b = blockIdx.y, mt = blockIdx.x;
    const int t = threadIdx.x;
    const long qrow0 = (long)b * Mm + mt * 32;

#pragma unroll
    for (int r = 0; r < 4; ++r) {
        int e = (r * 256 + t) * 8;
        bf16x8 qv = *(const bf16x8*)(qb + qrow0 * 256 + e);
        f32x4 lo = {(float)qv[0], (float)qv[1], (float)qv[2], (float)qv[3]};
        f32x4 hi = {(float)qv[4], (float)qv[5], (float)qv[6], (float)qv[7]};
        *(f32x4*)&lqf[e] = lo;
        *(f32x4*)&lqf[e + 4] = hi;
    }
    lz[t & 255] = zb[qrow0 * 8 + (t & 255)];

    float kv0[32], kv1[32];
    const float* kvb = kvagg + (long)b * (Hh * 64 * 32);
#pragma unroll
    for (int d4 = 0; d4 < 8; ++d4) {
        *(f32x4*)&kv0[d4 * 4] = *(const f32x4*)&kvb[(long)t * 32 + d4 * 4];
        *(f32x4*)&kv1[d4 * 4] = *(const f32x4*)&kvb[((long)t + 256) * 32 + d4 * 4];
    }
    __syncthreads();

    const int h0 = t >> 6;
    for (int r = 0; r < 32; ++r) {
        float a0 = 0.f, a1 = 0.f;
        const float* q0 = &lqf[r * 256 + h0 * 32];
        const float* q1 = q0 + 128;
#pragma unroll
        for (int d = 0; d < 32; ++d) {
            a0 = fmaf(q0[d], kv0[d], a0);
            a1 = fmaf(q1[d], kv1[d], a1);
        }
        const float z0 = lz[r * 8 + h0];
        const float z1 = lz[r * 8 + h0 + 4];
        const long ob = (qrow0 + r) * 512;
        out[ob + t] = a0 * z0;
        out[ob + t + 256] = a1 * z1;
    }
}

// ---------------- launch ----------------------------------------------------
extern "C" void kernel_launch(void* const* d_in, const int* in_sizes, int n_in,
                              void* d_out, int out_size, void* d_ws, size_t ws_size,
                              hipStream_t stream)
{
    const float* X  = (const float*)d_in[0];
    const float* Qt = (const float*)d_in[1];
    const float* Wq = (const float*)d_in[2];
    const float* bq = (const float*)d_in[3];
    const float* Wk = (const float*)d_in[4];
    const float* bk = (const float*)d_in[5];
    const float* Wv = (const float*)d_in[6];
    const float* bv = (const float*)d_in[7];
    float* out = (float*)d_out;

    // workspace layout (~98 MB)
    __hip_bfloat16* Xb    = (__hip_bfloat16*)d_ws;                 // 32768*512
    __hip_bfloat16* Qb    = Xb + (long)32768 * 512;                // 8192*512
    __hip_bfloat16* Wkvt  = Qb + (long)8192 * 512;                 // 768*512
    __hip_bfloat16* Wqt   = Wkvt + 768 * 512;                      // 256*512
    __hip_bfloat16* kvT   = Wqt + 256 * 512;                       // 768*32768
    __hip_bfloat16* qbuf  = kvT + (long)768 * NTOK;                // 8192*256
    float* kvagg = (float*)(qbuf + (long)8192 * 256);              // 4*8*64*32
    float* ksum  = kvagg + 4 * 8 * 64 * 32;                        // 4*256
    float* zbuf  = ksum + 4 * 256;                                 // 8192*8
    // kvpart aliases Xb (Xb dead after the GEMMs; stream is serial): 4MB < 33.5MB
    float* kvpart = (float*)d_ws;

    convert_bf16<<<10240, 256, 0, stream>>>(X, Qt, Xb);
    transpose_w<<<2048, 256, 0, stream>>>(Wk, Wv, Wq, Wkvt, Wqt);
    gemm_bt<0><<<dim3(256, 6), 256, 0, stream>>>(Xb, Wkvt, bk, bv, kvT, 32768, 768, 512);
    gemm_bt<1><<<dim3(64, 2), 256, 0, stream>>>(Qb, Wqt, bq, nullptr, qbuf, 8192, 256, 512);
    kv_mfma<<<dim3(16, 8, 4), 256, 0, stream>>>(kvT, kvpart);
    ksum_kernel<<<dim3(256, 4), 256, 0, stream>>>(kvT, ksum);
    reduce_kv<<<256, 256, 0, stream>>>(kvpart, kvagg);
    z_kernel<<<256, 256, 0, stream>>>(qbuf, ksum, zbuf);
    out_kernel<<<dim3(64, 4), 256, 0, stream>>>(qbuf, kvagg, zbuf, out);
}